// Round 1
// baseline (649.036 us; speedup 1.0000x reference)
//
#include <hip/hip_runtime.h>

#define DI __device__ __forceinline__

DI float silu_f(float x) { return x / (1.f + __expf(-x)); }
DI float sigmoid_f(float x) { return 1.f / (1.f + __expf(-x)); }
DI int reflect_i(int i, int n) { if (i < 0) i = -i; if (i >= n) i = 2 * n - 2 - i; return i; }

// K1: bilinear resize (2,3,1024,1024) -> (2,3,256,256), align-corners style
__global__ void k_resize(const float* __restrict__ img, float* __restrict__ x) {
    int idx = blockIdx.x * blockDim.x + threadIdx.x;
    if (idx >= 2 * 3 * 256 * 256) return;
    int ox = idx & 255;
    int oy = (idx >> 8) & 255;
    int bc = idx >> 16;  // [0,6)
    float py = oy * (1023.f / 255.f);
    float px = ox * (1023.f / 255.f);
    int iy0 = (int)floorf(py); if (iy0 > 1022) iy0 = 1022; float fy = py - (float)iy0;
    int ix0 = (int)floorf(px); if (ix0 > 1022) ix0 = 1022; float fx = px - (float)ix0;
    const float* p = img + (size_t)bc * 1024 * 1024;
    float a00 = p[iy0 * 1024 + ix0],       a01 = p[iy0 * 1024 + ix0 + 1];
    float a10 = p[(iy0 + 1) * 1024 + ix0], a11 = p[(iy0 + 1) * 1024 + ix0 + 1];
    float r0 = a00 + fy * (a10 - a00);  // interp along H (axis 2) first
    float r1 = a01 + fy * (a11 - a01);
    x[idx] = r0 + fx * (r1 - r0);
}

// Generic 3x3 conv, reflect pad 1, stride s, optional SiLU. One thread per output.
__global__ void k_conv3x3(const float* __restrict__ in, const float* __restrict__ w,
                          const float* __restrict__ bias, float* __restrict__ out,
                          int B, int Cin, int Hin, int Win,
                          int Cout, int Hout, int Wout, int stride) {
    int idx = blockIdx.x * blockDim.x + threadIdx.x;
    int total = B * Cout * Hout * Wout;
    if (idx >= total) return;
    int ox = idx % Wout;
    int t = idx / Wout;
    int oy = t % Hout; t /= Hout;
    int oc = t % Cout;
    int bb = t / Cout;
    float sum = bias[oc];
    const float* wp = w + (size_t)oc * Cin * 9;
    const float* ip = in + (size_t)bb * Cin * Hin * Win;
    int iy[3], ix[3];
#pragma unroll
    for (int k = 0; k < 3; ++k) {
        iy[k] = reflect_i(oy * stride + k - 1, Hin);
        ix[k] = reflect_i(ox * stride + k - 1, Win);
    }
    for (int ic = 0; ic < Cin; ++ic) {
        const float* ipc = ip + (size_t)ic * Hin * Win;
        const float* wpc = wp + ic * 9;
#pragma unroll
        for (int ky = 0; ky < 3; ++ky) {
            const float* row = ipc + iy[ky] * Win;
#pragma unroll
            for (int kx = 0; kx < 3; ++kx) {
                sum = fmaf(row[ix[kx]], wpc[ky * 3 + kx], sum);
            }
        }
    }
    out[idx] = silu_f(sum);
}

// K6: fused avg-pool + concat -> feat (2,480,8,8)
__global__ void k_pool(const float* __restrict__ c1, const float* __restrict__ c2,
                       const float* __restrict__ c3, const float* __restrict__ c4,
                       float* __restrict__ feat) {
    int idx = blockIdx.x * blockDim.x + threadIdx.x;
    if (idx >= 2 * 480 * 64) return;
    int x = idx & 7;
    int y = (idx >> 3) & 7;
    int fc = (idx >> 6) % 480;
    int bb = idx / (480 * 64);
    const float* src; int C, HW, k, c;
    if (fc < 32)       { src = c1; C = 32;  HW = 128; k = 16; c = fc; }
    else if (fc < 96)  { src = c2; C = 64;  HW = 64;  k = 8;  c = fc - 32; }
    else if (fc < 224) { src = c3; C = 128; HW = 32;  k = 4;  c = fc - 96; }
    else               { src = c4; C = 256; HW = 16;  k = 2;  c = fc - 224; }
    const float* p = src + ((size_t)bb * C + c) * HW * HW + (y * k) * HW + x * k;
    float s = 0.f;
    for (int i = 0; i < k; ++i)
        for (int j = 0; j < k; ++j) s += p[i * HW + j];
    feat[idx] = s / (float)(k * k);
}

// K7: lin1 = 3x3 reflect conv 480->128 on 8x8 + SiLU. 16 lanes per output, split over ic.
__global__ void k_lin1(const float* __restrict__ feat, const float* __restrict__ w,
                       const float* __restrict__ bias, float* __restrict__ h1) {
    int gid = (blockIdx.x * blockDim.x + threadIdx.x) >> 4;
    int lane = threadIdx.x & 15;
    if (gid >= 2 * 128 * 8 * 8) return;
    int ox = gid & 7;
    int oy = (gid >> 3) & 7;
    int oc = (gid >> 6) & 127;
    int bb = gid >> 13;
    const float* fp = feat + (size_t)bb * 480 * 64;
    const float* wp = w + (size_t)oc * 480 * 9;
    int iy[3], ix[3];
#pragma unroll
    for (int k = 0; k < 3; ++k) {
        iy[k] = reflect_i(oy + k - 1, 8);
        ix[k] = reflect_i(ox + k - 1, 8);
    }
    float sum = 0.f;
    for (int ic = lane; ic < 480; ic += 16) {
        const float* fpc = fp + ic * 64;
        const float* wpc = wp + ic * 9;
#pragma unroll
        for (int ky = 0; ky < 3; ++ky) {
#pragma unroll
            for (int kx = 0; kx < 3; ++kx) {
                sum = fmaf(fpc[iy[ky] * 8 + ix[kx]], wpc[ky * 3 + kx], sum);
            }
        }
    }
    sum += __shfl_xor(sum, 8, 64);
    sum += __shfl_xor(sum, 4, 64);
    sum += __shfl_xor(sum, 2, 64);
    sum += __shfl_xor(sum, 1, 64);
    if (lane == 0) h1[gid] = silu_f(sum + bias[oc]);
}

// K8: lin2 = 1x1 conv 128->27 + sigmoid -> wl (2,27,8,8)
__global__ void k_lin2(const float* __restrict__ h1, const float* __restrict__ w,
                       const float* __restrict__ bias, float* __restrict__ wl) {
    int idx = blockIdx.x * blockDim.x + threadIdx.x;
    if (idx >= 2 * 27 * 64) return;
    int pix = idx & 63;
    int oc = (idx >> 6) % 27;
    int bb = idx / (27 * 64);
    const float* hp = h1 + (size_t)bb * 128 * 64 + pix;
    const float* wp = w + oc * 128;
    float sum = bias[oc];
    for (int ic = 0; ic < 128; ++ic) sum = fmaf(hp[ic * 64], wp[ic], sum);
    wl[((size_t)bb * 27 + oc) * 64 + pix] = sigmoid_f(sum);
}

// K9: fused bilinear-upsample of wl + LUT interp + weighted sum + clip.
__global__ void k_apply(const float* __restrict__ img, const float* __restrict__ wl,
                        const float* __restrict__ luts, float* __restrict__ out) {
    __shared__ float slut[3 * 9 * 256];
    for (int i = threadIdx.x; i < 3 * 9 * 256; i += blockDim.x) slut[i] = luts[i];
    __syncthreads();
    int idx = blockIdx.x * blockDim.x + threadIdx.x;
    if (idx >= 2 * 3 * 1024 * 1024) return;
    int w = idx & 1023;
    int h = (idx >> 10) & 1023;
    int c = (idx >> 20) % 3;
    int bb = idx / (3 * 1024 * 1024);
    float py = h * (7.f / 1023.f);
    int iy0 = (int)floorf(py); if (iy0 > 6) iy0 = 6; float fy = py - (float)iy0;
    float px = w * (7.f / 1023.f);
    int ix0 = (int)floorf(px); if (ix0 > 6) ix0 = 6; float fx = px - (float)ix0;
    float w00 = (1.f - fy) * (1.f - fx), w01 = (1.f - fy) * fx;
    float w10 = fy * (1.f - fx),         w11 = fy * fx;
    float p = img[idx];
    p = fminf(fmaxf(p, 0.f), 1.f) * 255.f;
    int i0 = (int)floorf(p); if (i0 > 254) i0 = 254;
    float fr = p - (float)i0;
    const float* wlb = wl + ((size_t)bb * 27 + c * 9) * 64;
    const float* lc = slut + c * 9 * 256;
    float acc = 0.f;
#pragma unroll
    for (int k = 0; k < 9; ++k) {
        const float* q = wlb + k * 64 + iy0 * 8 + ix0;
        float wt = w00 * q[0] + w01 * q[1] + w10 * q[8] + w11 * q[9];
        float l0 = lc[k * 256 + i0], l1 = lc[k * 256 + i0 + 1];
        acc = fmaf(wt, fmaf(fr, l1 - l0, l0), acc);
    }
    out[idx] = fminf(fmaxf(acc, 0.f), 1.f);
}

extern "C" void kernel_launch(void* const* d_in, const int* in_sizes, int n_in,
                              void* d_out, int out_size, void* d_ws, size_t ws_size,
                              hipStream_t stream) {
    const float* img     = (const float*)d_in[0];
    const float* conv1_w = (const float*)d_in[1];
    const float* conv1_b = (const float*)d_in[2];
    const float* conv2_w = (const float*)d_in[3];
    const float* conv2_b = (const float*)d_in[4];
    const float* conv3_w = (const float*)d_in[5];
    const float* conv3_b = (const float*)d_in[6];
    const float* conv4_w = (const float*)d_in[7];
    const float* conv4_b = (const float*)d_in[8];
    const float* lin1_w  = (const float*)d_in[9];
    const float* lin1_b  = (const float*)d_in[10];
    const float* lin2_w  = (const float*)d_in[11];
    const float* lin2_b  = (const float*)d_in[12];
    const float* luts    = (const float*)d_in[13];
    float* out = (float*)d_out;

    float* ws = (float*)d_ws;
    float* x_rs = ws;            ws += 2 * 3 * 256 * 256;     // 393216
    float* c1   = ws;            ws += 2 * 32 * 128 * 128;    // 1048576
    float* c2   = ws;            ws += 2 * 64 * 64 * 64;      // 524288
    float* c3   = ws;            ws += 2 * 128 * 32 * 32;     // 262144
    float* c4   = ws;            ws += 2 * 256 * 16 * 16;     // 131072
    float* feat = ws;            ws += 2 * 480 * 8 * 8;       // 61440
    float* h1   = ws;            ws += 2 * 128 * 8 * 8;       // 16384
    float* wl   = ws;            ws += 2 * 27 * 8 * 8;        // 3456

    const int B = 256;
    k_resize<<<(2 * 3 * 256 * 256 + B - 1) / B, B, 0, stream>>>(img, x_rs);
    k_conv3x3<<<(2 * 32 * 128 * 128 + B - 1) / B, B, 0, stream>>>(
        x_rs, conv1_w, conv1_b, c1, 2, 3, 256, 256, 32, 128, 128, 2);
    k_conv3x3<<<(2 * 64 * 64 * 64 + B - 1) / B, B, 0, stream>>>(
        c1, conv2_w, conv2_b, c2, 2, 32, 128, 128, 64, 64, 64, 2);
    k_conv3x3<<<(2 * 128 * 32 * 32 + B - 1) / B, B, 0, stream>>>(
        c2, conv3_w, conv3_b, c3, 2, 64, 64, 64, 128, 32, 32, 2);
    k_conv3x3<<<(2 * 256 * 16 * 16 + B - 1) / B, B, 0, stream>>>(
        c3, conv4_w, conv4_b, c4, 2, 128, 32, 32, 256, 16, 16, 2);
    k_pool<<<(2 * 480 * 64 + B - 1) / B, B, 0, stream>>>(c1, c2, c3, c4, feat);
    k_lin1<<<(2 * 128 * 64 * 16 + B - 1) / B, B, 0, stream>>>(feat, lin1_w, lin1_b, h1);
    k_lin2<<<(2 * 27 * 64 + B - 1) / B, B, 0, stream>>>(h1, lin2_w, lin2_b, wl);
    k_apply<<<(2 * 3 * 1024 * 1024 + B - 1) / B, B, 0, stream>>>(img, wl, luts, out);
}